// Round 16
// baseline (50.938 us; speedup 1.0000x reference)
//
#include <hip/hip_runtime.h>
#include <hip/hip_fp16.h>
#include <math.h>

#define EE 64
#define HH 128
#define DD 256
#define MHID 512
#define NSC 32
#define PPED 64
#define NTOT 2048
#define TILE 16
#define PPS 1024

typedef __attribute__((ext_vector_type(8))) short short8;
typedef __attribute__((ext_vector_type(4))) float f32x4;
typedef _Float16 half8 __attribute__((ext_vector_type(8)));

// workspace layout (bytes)
// W2T/WPT FRAG-BLOCKED: element (col,k), k = ks*32+g*8+e -> col*512 + g*128 + ks*8 + e
static const size_t U16_OFF = 16384;
static const size_t V16_OFF = U16_OFF + (size_t)NTOT * MHID * 2;
static const size_t W2T_OFF = V16_OFF + (size_t)NTOT * MHID * 2;
static const size_t WPT_OFF = W2T_OFF + (size_t)DD * MHID * 2;
static const size_t PAIR_OFF = WPT_OFF + (size_t)DD * MHID * 2;
static const size_t SCNT_OFF = PAIR_OFF + (size_t)NSC * PPS * 4;
static const size_t PSTART_OFF = SCNT_OFF + 4096;
static const size_t PCNT_OFF = PSTART_OFF + (size_t)NTOT * 4;

__device__ __forceinline__ unsigned short f2bf(float f) {
  unsigned int u = __float_as_uint(f);
  return (unsigned short)((u + 0x7fffu + ((u >> 16) & 1u)) >> 16);
}
__device__ __forceinline__ unsigned short f2h(float f) {
  return __half_as_ushort(__float2half(f));
}

// ====== kA: 256 blocks, single occupancy wave.
//   All blocks: U/V GEMM for (bx = b>>2, by = b&3).
//   Blocks 0..31 additionally: scene mask + pair compaction.
//   Blocks 32..63 additionally: W2T/WpT transpose slab. ======
__global__ __launch_bounds__(256) void kA(
    const float* __restrict__ hstates, const float* __restrict__ pos,
    const float* __restrict__ vel, const float* __restrict__ bpos,
    const float* __restrict__ Ws, const float* __restrict__ bs,
    const float* __restrict__ Wv, const float* __restrict__ bv,
    const float* __restrict__ Wm1, const float* __restrict__ bm1,
    const float* __restrict__ Wm2, const float* __restrict__ Wp,
    float* __restrict__ ws) {
  __shared__ __align__(16) char smem[44544];
  int b = blockIdx.x;
  int tid = threadIdx.x;
  // ---------------- phase 1: U/V via MFMA f16 (all 256 blocks) ----------------
  {
    unsigned short* Ash = (unsigned short*)smem;
    _Float16* Bsh = (_Float16*)(smem + 8448);  // [128][130]
    float* csh = (float*)(smem + 8448 + 33280);
    unsigned short* u16 = (unsigned short*)((char*)ws + U16_OFF);
    unsigned short* v16 = (unsigned short*)((char*)ws + V16_OFF);
    int bx = b >> 2, by = b & 3;
    int n0 = bx * 32, C0 = by * 128;
    {
      int p = tid >> 3, kq = (tid & 7) * 16;
      const float* hp = hstates + (size_t)(n0 + p) * HH + kq;
      float4 f0 = *(const float4*)(hp);
      float4 f1 = *(const float4*)(hp + 4);
      float4 f2 = *(const float4*)(hp + 8);
      float4 f3 = *(const float4*)(hp + 12);
      int swz = (p & 7) << 3;
      uint4 v0, v1;
      v0.x = f2h(f0.x) | ((unsigned int)f2h(f0.y) << 16);
      v0.y = f2h(f0.z) | ((unsigned int)f2h(f0.w) << 16);
      v0.z = f2h(f1.x) | ((unsigned int)f2h(f1.y) << 16);
      v0.w = f2h(f1.z) | ((unsigned int)f2h(f1.w) << 16);
      v1.x = f2h(f2.x) | ((unsigned int)f2h(f2.y) << 16);
      v1.y = f2h(f2.z) | ((unsigned int)f2h(f2.w) << 16);
      v1.z = f2h(f3.x) | ((unsigned int)f2h(f3.y) << 16);
      v1.w = f2h(f3.z) | ((unsigned int)f2h(f3.w) << 16);
      *(uint4*)(Ash + ((p * HH + kq) ^ swz)) = v0;
      *(uint4*)(Ash + ((p * HH + kq + 8) ^ swz)) = v1;
    }
#pragma unroll 4
    for (int it = 0; it < 16; ++it) {
      int flat = it * 1024 + tid * 4;
      int k = flat >> 7, col = flat & 127;
      float4 f = *(const float4*)&Wm1[(size_t)(2 * EE + k) * MHID + C0 + col];
      unsigned int* d = (unsigned int*)&Bsh[k * 130 + col];
      d[0] = (unsigned int)f2h(f.x) | ((unsigned int)f2h(f.y) << 16);
      d[1] = (unsigned int)f2h(f.z) | ((unsigned int)f2h(f.w) << 16);
    }
    if (tid < 128) {
      int col = C0 + tid;
      float a0 = 0.f, a1 = 0.f, b0 = 0.f, b1 = 0.f, cs = 0.f, cv = 0.f;
      for (int e = 0; e < EE; ++e) {
        float w1 = Wm1[(size_t)e * MHID + col];
        float w2 = Wm1[(size_t)(EE + e) * MHID + col];
        a0 = fmaf(Ws[e], w1, a0);
        a1 = fmaf(Ws[EE + e], w1, a1);
        b0 = fmaf(Wv[e], w2, b0);
        b1 = fmaf(Wv[EE + e], w2, b1);
        cs = fmaf(bs[e], w1, cs);
        cv = fmaf(bv[e], w2, cv);
      }
      csh[tid] = a0;
      csh[128 + tid] = a1;
      csh[256 + tid] = b0;
      csh[384 + tid] = b1;
      csh[512 + tid] = bm1[col] + cs + cv;
    }
    __syncthreads();
    int w = tid >> 6, l = tid & 63;
    int lr = l & 15, lg = l >> 4;
    f32x4 acc[2][2];
#pragma unroll
    for (int i = 0; i < 2; ++i)
#pragma unroll
      for (int j = 0; j < 2; ++j) acc[i][j] = (f32x4){0.f, 0.f, 0.f, 0.f};
    int aswz = (lr & 7) << 3;
    int colr0 = w * 32 + lr, colr1 = colr0 + 16;
#pragma unroll
    for (int ks = 0; ks < 4; ++ks) {
      int k0 = ks * 32 + lg * 8;
      half8 a0 = *(const half8*)(Ash + ((lr * HH + k0) ^ aswz));
      half8 a1 = *(const half8*)(Ash + (((16 + lr) * HH + k0) ^ aswz));
      half8 b0, b1;
#pragma unroll
      for (int e = 0; e < 8; ++e) {
        b0[e] = Bsh[(k0 + e) * 130 + colr0];
        b1[e] = Bsh[(k0 + e) * 130 + colr1];
      }
      acc[0][0] = __builtin_amdgcn_mfma_f32_16x16x32_f16(a0, b0, acc[0][0], 0, 0, 0);
      acc[0][1] = __builtin_amdgcn_mfma_f32_16x16x32_f16(a0, b1, acc[0][1], 0, 0, 0);
      acc[1][0] = __builtin_amdgcn_mfma_f32_16x16x32_f16(a1, b0, acc[1][0], 0, 0, 0);
      acc[1][1] = __builtin_amdgcn_mfma_f32_16x16x32_f16(a1, b1, acc[1][1], 0, 0, 0);
    }
#pragma unroll
    for (int ct = 0; ct < 2; ++ct) {
      int colr = w * 32 + ct * 16 + lr;
      int col = C0 + colr;
      float a0c = csh[colr], a1c = csh[128 + colr], b0c = csh[256 + colr],
            b1c = csh[384 + colr], cc = csh[512 + colr];
#pragma unroll
      for (int rt = 0; rt < 2; ++rt) {
#pragma unroll
        for (int r = 0; r < 4; ++r) {
          int row = n0 + rt * 16 + lg * 4 + r;
          float px = pos[row * 2], py = pos[row * 2 + 1];
          float vx = vel[row * 2], vy = vel[row * 2 + 1];
          float base = px * a0c + py * a1c + vx * b0c + vy * b1c;
          u16[(size_t)row * MHID + col] = f2h(acc[rt][ct][r] + base + cc);
          v16[(size_t)row * MHID + col] = f2h(base);
        }
      }
    }
  }
  if (b >= 64) return;
  __syncthreads();  // U/V phase done; smem free for aux phase
  if (b < 32) {
    // ---------------- aux: scene mask + in-LDS compaction ----------------
    char* raw = smem;
    double* sx = (double*)raw;
    double* sy = (double*)(raw + 512);
    int* cnt_sh = (int*)(raw + 1024);
    int* pref_sh = (int*)(raw + 1280);
    unsigned long long* mwp = (unsigned long long*)(raw + 1536);
    int scene = b;
    int i = tid & 63;
    int jg = tid >> 6;
    int n = scene * PPED + i;
    if (tid < PPED) {
      sx[i] = (double)pos[n * 2];
      sy[i] = (double)pos[n * 2 + 1];
    }
    __syncthreads();
    {
      double px = sx[i], py = sy[i];
      double xb = (double)bpos[n * 2], yb = (double)bpos[n * 2 + 1];
      double xr = px - xb, yr = py - yb;
      double safe = (xr == 0.0) ? 1.0 : fabs(xr);
      double at = atan(fabs(yr) / safe);
      const double r90 = M_PI / 2.0, r180 = M_PI, r270 = 3.0 * M_PI / 2.0;
      double ang;
      if (xr > 0.0 && yr > 0.0) ang = at + r270;
      else if (xr < 0.0 && yr > 0.0) ang = r90 - at;
      else if (xr < 0.0 && yr < 0.0) ang = r90 + at;
      else if (xr > 0.0 && yr < 0.0) ang = r270 - at;
      else if (xr == 0.0 && yr > 0.0) ang = 0.0;
      else if (xr == 0.0 && yr < 0.0) ang = r180;
      else if (yr == 0.0 && xr > 0.0) ang = r270;
      else if (yr == 0.0 && xr < 0.0) ang = r90;
      else ang = 0.0;
      double cd = cos(ang), sd = sin(ang);
      const double cc2 = 2.0 / cos(60.0 * M_PI / 180.0);
      const double bb = sin(60.0 * M_PI / 180.0) * cc2;
      unsigned long long mw = 0ull;
      for (int j = jg * 16; j < jg * 16 + 16; ++j) {
        if (j == i) continue;
        double dx = sx[j] - px, dy = sy[j] - py;
        double xt = cd * dx - sd * dy;
        double yt = sd * dx + cd * dy;
        double res = (yt >= 0.0) ? (xt * xt + yt * yt / 4.0) : (xt * xt + yt * yt);
        bool egg = (res <= 1.0);
        double c1 = 2.0 * xt + bb * yt;
        double c2 = 2.0 * xt - bb * yt;
        bool cone = (c1 > 0.0 && c2 < 0.0) || (c1 == 0.0) || (c2 == 0.0);
        if (egg && (yt >= 0.0) && cone) mw |= (1ull << j);
      }
      mwp[jg * 64 + i] = mw;
    }
    __syncthreads();
    unsigned long long mw = 0ull;
    if (tid < PPED) {
      mw = mwp[i] | mwp[64 + i] | mwp[128 + i] | mwp[192 + i];
      cnt_sh[i] = __popcll(mw);
    }
    __syncthreads();
    if (tid == 0) {
      int run = 0;
      for (int j = 0; j < PPED; ++j) {
        pref_sh[j] = run;
        run += cnt_sh[j];
      }
      ((unsigned int*)((char*)ws + SCNT_OFF))[scene] =
          (unsigned int)((run > PPS) ? PPS : run);
    }
    __syncthreads();
    if (tid < PPED) {
      int c = cnt_sh[i];
      int basep = pref_sh[i];
      if (basep > PPS) basep = PPS;
      int lim = PPS - basep;
      if (lim > c) lim = c;
      ((unsigned int*)((char*)ws + PSTART_OFF))[n] = (unsigned int)(scene * PPS + basep);
      ((unsigned int*)((char*)ws + PCNT_OFF))[n] = (unsigned int)lim;
      unsigned int* pairs = (unsigned int*)((char*)ws + PAIR_OFF) + scene * PPS;
      unsigned long long rem = mw;
      unsigned int hi = ((unsigned int)n) << 16;
      for (int q = 0; q < lim; ++q) {
        int j = __builtin_ctzll(rem);
        rem &= rem - 1;
        pairs[basep + q] = hi | (unsigned int)(scene * PPED + j);
      }
    }
  } else {
    // ---------------- aux: W2T(fp16) / WpT(bf16) transpose slab ----------------
    unsigned short* Tsh = (unsigned short*)smem;
    int slab = b - 32;           // 0..31
    bool isW2 = (slab < 16);
    const float* src = isW2 ? Wm2 : Wp;
    unsigned short* dst = (unsigned short*)((char*)ws + (isW2 ? W2T_OFF : WPT_OFF));
    int c0 = (slab & 15) * 16;
#pragma unroll 4
    for (int it = 0; it < 32; ++it) {
      int k = it * 16 + (tid >> 4);
      int c = tid & 15;
      float v = src[(size_t)k * DD + c0 + c];
      Tsh[c * MHID + k] = isW2 ? f2h(v) : f2bf(v);
    }
    __syncthreads();
    unsigned int* dst32 = (unsigned int*)dst;
#pragma unroll 4
    for (int it = 0; it < 16; ++it) {
      int flat = it * 256 + tid;
      int c = flat >> 8;
      int ku = flat & 255;
      unsigned int lo = Tsh[c * MHID + 2 * ku];
      unsigned int hi = Tsh[c * MHID + 2 * ku + 1];
      int ks = ku >> 4;
      int g = (ku >> 2) & 3;
      int r = ku & 3;
      dst32[(size_t)(c0 + c) * 256 + g * 64 + ks * 4 + r] = lo | (hi << 16);
    }
  }
}

// ====== kCD: block owns 16 peds — layer2 tiles (LDS H2) + run-scan pool + final GEMM ======
__global__ __launch_bounds__(256) void kCD(const float* __restrict__ ws,
                                           const float* __restrict__ bm2,
                                           const float* __restrict__ bp,
                                           float* __restrict__ out) {
  __shared__ __align__(16) float catt[16 * 512 + 32];  // 32 KB cat tile (mx|mn)
  __shared__ __align__(16) char ashraw[16 * MHID * 2]; // 16 KB: Ash fp16 / H2t f32
  __shared__ int si[TILE], sjj[TILE];
  __shared__ int lse[17];
  int m0 = blockIdx.x * 16;
  int s = m0 >> 6;
  int tid = threadIdx.x;
  int w = tid >> 6, l = tid & 63;
  int lr = l & 15, lg = l >> 4;
  const unsigned short* u16 = (const unsigned short*)((const char*)ws + U16_OFF);
  const unsigned short* v16 = (const unsigned short*)((const char*)ws + V16_OFF);
  const _Float16* w2t = (const _Float16*)((const char*)ws + W2T_OFF);
  const short* wpt = (const short*)((const char*)ws + WPT_OFF);
  const unsigned int* pstart = (const unsigned int*)((const char*)ws + PSTART_OFF);
  const unsigned int* pcnt = (const unsigned int*)((const char*)ws + PCNT_OFF);
  const unsigned int* parr = (const unsigned int*)((const char*)ws + PAIR_OFF) + s * PPS;
  for (int i = tid; i < 16 * 512; i += 256) catt[i] = 0.f;
  if (tid < 16) {
    int n = m0 + tid;
    int ls = (int)pstart[n] - s * PPS;
    lse[tid] = ls;
    if (tid == 15) lse[16] = ls + (int)pcnt[n];
  }
  __syncthreads();
  int b0 = lse[0], b1 = lse[16];
  unsigned short* Ash = (unsigned short*)ashraw;
  float* H2t = (float*)ashraw;
  float rmx = 0.f, rmn = 0.f;
  int cur = -1;
  int col = tid;  // scan column
  float bias0 = bm2[w * 64 + lr];
  float bias1 = bm2[w * 64 + 16 + lr];
  float bias2 = bm2[w * 64 + 32 + lr];
  float bias3 = bm2[w * 64 + 48 + lr];
  for (int t0 = b0; t0 < b1; t0 += TILE) {
    __syncthreads();  // previous scan done (H2t/si free); catt init visible
    if (tid < TILE) {
      int p = t0 + tid;
      unsigned int pk = (p < b1) ? parr[p] : parr[b0];
      si[tid] = (int)(pk >> 16);
      sjj[tid] = (int)(pk & 0xFFFFu);
    }
    __syncthreads();
    // stage A: h1 = relu(U16[j] - V16[i]) fp16, XOR-swizzled
    {
      int pr = tid & 15, seg = tid >> 4;
      int jj = sjj[pr], ii = si[pr];
      const unsigned short* Up = u16 + (size_t)jj * MHID + seg * 32;
      const unsigned short* Vp = v16 + (size_t)ii * MHID + seg * 32;
      int swz = (pr & 7) << 3;
#pragma unroll
      for (int q = 0; q < 4; ++q) {
        half8 hu = *(const half8*)(Up + q * 8);
        half8 hv = *(const half8*)(Vp + q * 8);
        half8 d;
#pragma unroll
        for (int e = 0; e < 8; ++e) {
          _Float16 x = hu[e] - hv[e];
          d[e] = (x > (_Float16)0) ? x : (_Float16)0;
        }
        *(half8*)(Ash + ((pr * MHID + seg * 32 + q * 8) ^ swz)) = d;
      }
    }
    __syncthreads();
    // MFMA: wave w covers cols w*64 + cg*16 + lr, cg = 0..3
    int aswz = (lr & 7) << 3;
    f32x4 a0v = {0.f, 0.f, 0.f, 0.f}, a1v = {0.f, 0.f, 0.f, 0.f};
    f32x4 a2v = {0.f, 0.f, 0.f, 0.f}, a3v = {0.f, 0.f, 0.f, 0.f};
    const _Float16* wb0 = w2t + (size_t)(w * 64 + lr) * MHID + lg * 128;
#pragma unroll
    for (int ks = 0; ks < 16; ++ks) {
      half8 a = *(const half8*)(Ash + ((lr * MHID + ks * 32 + lg * 8) ^ aswz));
      half8 bf0 = *(const half8*)(wb0 + ks * 8);
      half8 bf1 = *(const half8*)(wb0 + 16 * MHID + ks * 8);
      half8 bf2 = *(const half8*)(wb0 + 32 * MHID + ks * 8);
      half8 bf3 = *(const half8*)(wb0 + 48 * MHID + ks * 8);
      a0v = __builtin_amdgcn_mfma_f32_16x16x32_f16(a, bf0, a0v, 0, 0, 0);
      a1v = __builtin_amdgcn_mfma_f32_16x16x32_f16(a, bf1, a1v, 0, 0, 0);
      a2v = __builtin_amdgcn_mfma_f32_16x16x32_f16(a, bf2, a2v, 0, 0, 0);
      a3v = __builtin_amdgcn_mfma_f32_16x16x32_f16(a, bf3, a3v, 0, 0, 0);
    }
    __syncthreads();  // all Ash reads complete; alias as H2t
#pragma unroll
    for (int r = 0; r < 4; ++r) {
      int row = lg * 4 + r;
      H2t[row * 256 + w * 64 + lr] = fmaxf(a0v[r] + bias0, 0.f);
      H2t[row * 256 + w * 64 + 16 + lr] = fmaxf(a1v[r] + bias1, 0.f);
      H2t[row * 256 + w * 64 + 32 + lr] = fmaxf(a2v[r] + bias2, 0.f);
      H2t[row * 256 + w * 64 + 48 + lr] = fmaxf(a3v[r] + bias3, 0.f);
    }
    __syncthreads();
    // run-scan pooling, state carried across tiles; thread owns col=tid
    int lastv = b1 - t0;
    if (lastv > TILE) lastv = TILE;
    for (int r = 0; r < lastv; ++r) {
      int ii = si[r];
      float v = H2t[r * 256 + col];
      if (ii != cur) {
        if (cur >= 0) {
          int li = cur - m0;
          int sz = (li & 7) << 2;
          catt[(li * 512 + col) ^ sz] = rmx;
          catt[(li * 512 + 256 + col) ^ sz] = rmn;
        }
        cur = ii;
        rmx = v;
        rmn = v;
      } else {
        rmx = fmaxf(rmx, v);
        rmn = fminf(rmn, v);
      }
    }
  }
  if (cur >= 0) {
    int li = cur - m0;
    int sz = (li & 7) << 2;
    catt[(li * 512 + col) ^ sz] = rmx;
    catt[(li * 512 + 256 + col) ^ sz] = rmn;
  }
  __syncthreads();
  // final GEMM: out[m0..m0+15] = relu(cat @ Wp + bp)
  int arow = l & 15, agrp = l >> 4;
  int aswz2 = (arow & 7) << 2;
  const short* wpb0 = wpt + (size_t)(w * 64 + arow) * MHID + agrp * 128;
  f32x4 acc0 = {0.f, 0.f, 0.f, 0.f}, acc1 = {0.f, 0.f, 0.f, 0.f};
  f32x4 acc2 = {0.f, 0.f, 0.f, 0.f}, acc3 = {0.f, 0.f, 0.f, 0.f};
#pragma unroll 4
  for (int ks = 0; ks < 16; ++ks) {
    int base = arow * 512 + ks * 32 + agrp * 8;
    float4 fa = *(const float4*)(catt + (base ^ aswz2));
    float4 fb = *(const float4*)(catt + ((base + 4) ^ aswz2));
    union {
      unsigned int u[4];
      short8 s;
    } av;
    av.u[0] = (unsigned int)f2bf(fa.x) | ((unsigned int)f2bf(fa.y) << 16);
    av.u[1] = (unsigned int)f2bf(fa.z) | ((unsigned int)f2bf(fa.w) << 16);
    av.u[2] = (unsigned int)f2bf(fb.x) | ((unsigned int)f2bf(fb.y) << 16);
    av.u[3] = (unsigned int)f2bf(fb.z) | ((unsigned int)f2bf(fb.w) << 16);
    short8 b0 = *(const short8*)(wpb0 + ks * 8);
    short8 b1 = *(const short8*)(wpb0 + 16 * MHID + ks * 8);
    short8 b2 = *(const short8*)(wpb0 + 32 * MHID + ks * 8);
    short8 b3 = *(const short8*)(wpb0 + 48 * MHID + ks * 8);
    acc0 = __builtin_amdgcn_mfma_f32_16x16x32_bf16(av.s, b0, acc0, 0, 0, 0);
    acc1 = __builtin_amdgcn_mfma_f32_16x16x32_bf16(av.s, b1, acc1, 0, 0, 0);
    acc2 = __builtin_amdgcn_mfma_f32_16x16x32_bf16(av.s, b2, acc2, 0, 0, 0);
    acc3 = __builtin_amdgcn_mfma_f32_16x16x32_bf16(av.s, b3, acc3, 0, 0, 0);
  }
#pragma unroll
  for (int t = 0; t < 4; ++t) {
    int colq = (w * 4 + t) * 16 + arow;
    float bias = bp[colq];
    f32x4 av = (t == 0) ? acc0 : (t == 1) ? acc1 : (t == 2) ? acc2 : acc3;
#pragma unroll
    for (int r = 0; r < 4; ++r) {
      int row = m0 + (l >> 4) * 4 + r;
      out[(size_t)row * DD + colq] = fmaxf(av[r] + bias, 0.f);
    }
  }
}

extern "C" void kernel_launch(void* const* d_in, const int* in_sizes, int n_in,
                              void* d_out, int out_size, void* d_ws, size_t ws_size,
                              hipStream_t stream) {
  const float* hstates = (const float*)d_in[0];
  const float* pos = (const float*)d_in[2];
  const float* vel = (const float*)d_in[3];
  const float* bpos = (const float*)d_in[4];
  const float* Ws = (const float*)d_in[5];
  const float* bs = (const float*)d_in[6];
  const float* Wv = (const float*)d_in[7];
  const float* bv = (const float*)d_in[8];
  const float* Wm1 = (const float*)d_in[9];
  const float* bm1 = (const float*)d_in[10];
  const float* Wm2 = (const float*)d_in[11];
  const float* bm2 = (const float*)d_in[12];
  const float* Wp = (const float*)d_in[13];
  const float* bp = (const float*)d_in[14];
  float* ws = (float*)d_ws;
  float* out = (float*)d_out;

  hipLaunchKernelGGL(kA, dim3(256), dim3(256), 0, stream, hstates, pos, vel, bpos, Ws, bs,
                     Wv, bv, Wm1, bm1, Wm2, Wp, ws);
  hipLaunchKernelGGL(kCD, dim3(NTOT / 16), dim3(256), 0, stream, ws, bm2, bp, out);
}

// Round 17
// 47.382 us; speedup vs baseline: 1.0751x; 1.0751x over previous
//
#include <hip/hip_runtime.h>
#include <hip/hip_fp16.h>
#include <math.h>

#define EE 64
#define HH 128
#define DD 256
#define MHID 512
#define NSC 32
#define PPED 64
#define NTOT 2048
#define TILE 16
#define PPS 1024

typedef __attribute__((ext_vector_type(8))) short short8;
typedef __attribute__((ext_vector_type(4))) float f32x4;
typedef _Float16 half8 __attribute__((ext_vector_type(8)));

// workspace layout (bytes)
// W2T/WPT FRAG-BLOCKED: element (col,k), k = ks*32+g*8+e -> col*512 + g*128 + ks*8 + e
static const size_t U16_OFF = 16384;
static const size_t V16_OFF = U16_OFF + (size_t)NTOT * MHID * 2;
static const size_t W2T_OFF = V16_OFF + (size_t)NTOT * MHID * 2;
static const size_t WPT_OFF = W2T_OFF + (size_t)DD * MHID * 2;
static const size_t PAIR_OFF = WPT_OFF + (size_t)DD * MHID * 2;
static const size_t SCNT_OFF = PAIR_OFF + (size_t)NSC * PPS * 4;
static const size_t PSTART_OFF = SCNT_OFF + 4096;
static const size_t PCNT_OFF = PSTART_OFF + (size_t)NTOT * 4;

__device__ __forceinline__ unsigned short f2bf(float f) {
  unsigned int u = __float_as_uint(f);
  return (unsigned short)((u + 0x7fffu + ((u >> 16) & 1u)) >> 16);
}
__device__ __forceinline__ unsigned short f2h(float f) {
  return __half_as_ushort(__float2half(f));
}

// ====== kA: self-contained U/V GEMM (0..255) + masks (256..287) +
//            W2T (288..303) + WpT (304..319) ======
__global__ __launch_bounds__(256) void kA(
    const float* __restrict__ hstates, const float* __restrict__ pos,
    const float* __restrict__ vel, const float* __restrict__ bpos,
    const float* __restrict__ Ws, const float* __restrict__ bs,
    const float* __restrict__ Wv, const float* __restrict__ bv,
    const float* __restrict__ Wm1, const float* __restrict__ bm1,
    const float* __restrict__ Wm2, const float* __restrict__ Wp,
    float* __restrict__ ws) {
  __shared__ __align__(16) char smem[44544];
  int b = blockIdx.x;
  int tid = threadIdx.x;
  if (b < 256) {
    unsigned short* Ash = (unsigned short*)smem;
    _Float16* Bsh = (_Float16*)(smem + 8448);  // [128][130]
    float* csh = (float*)(smem + 8448 + 33280);
    unsigned short* u16 = (unsigned short*)((char*)ws + U16_OFF);
    unsigned short* v16 = (unsigned short*)((char*)ws + V16_OFF);
    int bx = b >> 2, by = b & 3;
    int n0 = bx * 32, C0 = by * 128;
    {
      int p = tid >> 3, kq = (tid & 7) * 16;
      const float* hp = hstates + (size_t)(n0 + p) * HH + kq;
      float4 f0 = *(const float4*)(hp);
      float4 f1 = *(const float4*)(hp + 4);
      float4 f2 = *(const float4*)(hp + 8);
      float4 f3 = *(const float4*)(hp + 12);
      int swz = (p & 7) << 3;
      uint4 v0, v1;
      v0.x = f2h(f0.x) | ((unsigned int)f2h(f0.y) << 16);
      v0.y = f2h(f0.z) | ((unsigned int)f2h(f0.w) << 16);
      v0.z = f2h(f1.x) | ((unsigned int)f2h(f1.y) << 16);
      v0.w = f2h(f1.z) | ((unsigned int)f2h(f1.w) << 16);
      v1.x = f2h(f2.x) | ((unsigned int)f2h(f2.y) << 16);
      v1.y = f2h(f2.z) | ((unsigned int)f2h(f2.w) << 16);
      v1.z = f2h(f3.x) | ((unsigned int)f2h(f3.y) << 16);
      v1.w = f2h(f3.z) | ((unsigned int)f2h(f3.w) << 16);
      *(uint4*)(Ash + ((p * HH + kq) ^ swz)) = v0;
      *(uint4*)(Ash + ((p * HH + kq + 8) ^ swz)) = v1;
    }
#pragma unroll 4
    for (int it = 0; it < 16; ++it) {
      int flat = it * 1024 + tid * 4;
      int k = flat >> 7, col = flat & 127;
      float4 f = *(const float4*)&Wm1[(size_t)(2 * EE + k) * MHID + C0 + col];
      unsigned int* d = (unsigned int*)&Bsh[k * 130 + col];
      d[0] = (unsigned int)f2h(f.x) | ((unsigned int)f2h(f.y) << 16);
      d[1] = (unsigned int)f2h(f.z) | ((unsigned int)f2h(f.w) << 16);
    }
    if (tid < 128) {
      int col = C0 + tid;
      float a0 = 0.f, a1 = 0.f, b0 = 0.f, b1 = 0.f, cs = 0.f, cv = 0.f;
      for (int e = 0; e < EE; ++e) {
        float w1 = Wm1[(size_t)e * MHID + col];
        float w2 = Wm1[(size_t)(EE + e) * MHID + col];
        a0 = fmaf(Ws[e], w1, a0);
        a1 = fmaf(Ws[EE + e], w1, a1);
        b0 = fmaf(Wv[e], w2, b0);
        b1 = fmaf(Wv[EE + e], w2, b1);
        cs = fmaf(bs[e], w1, cs);
        cv = fmaf(bv[e], w2, cv);
      }
      csh[tid] = a0;
      csh[128 + tid] = a1;
      csh[256 + tid] = b0;
      csh[384 + tid] = b1;
      csh[512 + tid] = bm1[col] + cs + cv;
    }
    __syncthreads();
    int w = tid >> 6, l = tid & 63;
    int lr = l & 15, lg = l >> 4;
    f32x4 acc[2][2];
#pragma unroll
    for (int i = 0; i < 2; ++i)
#pragma unroll
      for (int j = 0; j < 2; ++j) acc[i][j] = (f32x4){0.f, 0.f, 0.f, 0.f};
    int aswz = (lr & 7) << 3;
    int colr0 = w * 32 + lr, colr1 = colr0 + 16;
#pragma unroll
    for (int ks = 0; ks < 4; ++ks) {
      int k0 = ks * 32 + lg * 8;
      half8 a0 = *(const half8*)(Ash + ((lr * HH + k0) ^ aswz));
      half8 a1 = *(const half8*)(Ash + (((16 + lr) * HH + k0) ^ aswz));
      half8 b0, b1;
#pragma unroll
      for (int e = 0; e < 8; ++e) {
        b0[e] = Bsh[(k0 + e) * 130 + colr0];
        b1[e] = Bsh[(k0 + e) * 130 + colr1];
      }
      acc[0][0] = __builtin_amdgcn_mfma_f32_16x16x32_f16(a0, b0, acc[0][0], 0, 0, 0);
      acc[0][1] = __builtin_amdgcn_mfma_f32_16x16x32_f16(a0, b1, acc[0][1], 0, 0, 0);
      acc[1][0] = __builtin_amdgcn_mfma_f32_16x16x32_f16(a1, b0, acc[1][0], 0, 0, 0);
      acc[1][1] = __builtin_amdgcn_mfma_f32_16x16x32_f16(a1, b1, acc[1][1], 0, 0, 0);
    }
#pragma unroll
    for (int ct = 0; ct < 2; ++ct) {
      int colr = w * 32 + ct * 16 + lr;
      int col = C0 + colr;
      float a0c = csh[colr], a1c = csh[128 + colr], b0c = csh[256 + colr],
            b1c = csh[384 + colr], cc = csh[512 + colr];
#pragma unroll
      for (int rt = 0; rt < 2; ++rt) {
#pragma unroll
        for (int r = 0; r < 4; ++r) {
          int row = n0 + rt * 16 + lg * 4 + r;
          float px = pos[row * 2], py = pos[row * 2 + 1];
          float vx = vel[row * 2], vy = vel[row * 2 + 1];
          float base = px * a0c + py * a1c + vx * b0c + vy * b1c;
          u16[(size_t)row * MHID + col] = f2h(acc[rt][ct][r] + base + cc);
          v16[(size_t)row * MHID + col] = f2h(base);
        }
      }
    }
  } else if (b < 288) {
    char* raw = smem;
    double* sx = (double*)raw;
    double* sy = (double*)(raw + 512);
    int* cnt_sh = (int*)(raw + 1024);
    int* pref_sh = (int*)(raw + 1280);
    unsigned long long* mwp = (unsigned long long*)(raw + 1536);
    int scene = b - 256;
    int i = tid & 63;
    int jg = tid >> 6;
    int n = scene * PPED + i;
    if (tid < PPED) {
      sx[i] = (double)pos[n * 2];
      sy[i] = (double)pos[n * 2 + 1];
    }
    __syncthreads();
    {
      double px = sx[i], py = sy[i];
      double xb = (double)bpos[n * 2], yb = (double)bpos[n * 2 + 1];
      double xr = px - xb, yr = py - yb;
      double safe = (xr == 0.0) ? 1.0 : fabs(xr);
      double at = atan(fabs(yr) / safe);
      const double r90 = M_PI / 2.0, r180 = M_PI, r270 = 3.0 * M_PI / 2.0;
      double ang;
      if (xr > 0.0 && yr > 0.0) ang = at + r270;
      else if (xr < 0.0 && yr > 0.0) ang = r90 - at;
      else if (xr < 0.0 && yr < 0.0) ang = r90 + at;
      else if (xr > 0.0 && yr < 0.0) ang = r270 - at;
      else if (xr == 0.0 && yr > 0.0) ang = 0.0;
      else if (xr == 0.0 && yr < 0.0) ang = r180;
      else if (yr == 0.0 && xr > 0.0) ang = r270;
      else if (yr == 0.0 && xr < 0.0) ang = r90;
      else ang = 0.0;
      double cd = cos(ang), sd = sin(ang);
      const double cc2 = 2.0 / cos(60.0 * M_PI / 180.0);
      const double bb = sin(60.0 * M_PI / 180.0) * cc2;
      unsigned long long mw = 0ull;
      for (int j = jg * 16; j < jg * 16 + 16; ++j) {
        if (j == i) continue;
        double dx = sx[j] - px, dy = sy[j] - py;
        double xt = cd * dx - sd * dy;
        double yt = sd * dx + cd * dy;
        double res = (yt >= 0.0) ? (xt * xt + yt * yt / 4.0) : (xt * xt + yt * yt);
        bool egg = (res <= 1.0);
        double c1 = 2.0 * xt + bb * yt;
        double c2 = 2.0 * xt - bb * yt;
        bool cone = (c1 > 0.0 && c2 < 0.0) || (c1 == 0.0) || (c2 == 0.0);
        if (egg && (yt >= 0.0) && cone) mw |= (1ull << j);
      }
      mwp[jg * 64 + i] = mw;
    }
    __syncthreads();
    unsigned long long mw = 0ull;
    if (tid < PPED) {
      mw = mwp[i] | mwp[64 + i] | mwp[128 + i] | mwp[192 + i];
      cnt_sh[i] = __popcll(mw);
    }
    __syncthreads();
    if (tid == 0) {
      int run = 0;
      for (int j = 0; j < PPED; ++j) {
        pref_sh[j] = run;
        run += cnt_sh[j];
      }
      ((unsigned int*)((char*)ws + SCNT_OFF))[scene] =
          (unsigned int)((run > PPS) ? PPS : run);
    }
    __syncthreads();
    if (tid < PPED) {
      int c = cnt_sh[i];
      int basep = pref_sh[i];
      if (basep > PPS) basep = PPS;
      int lim = PPS - basep;
      if (lim > c) lim = c;
      ((unsigned int*)((char*)ws + PSTART_OFF))[n] = (unsigned int)(scene * PPS + basep);
      ((unsigned int*)((char*)ws + PCNT_OFF))[n] = (unsigned int)lim;
      unsigned int* pairs = (unsigned int*)((char*)ws + PAIR_OFF) + scene * PPS;
      unsigned long long rem = mw;
      unsigned int hi = ((unsigned int)n) << 16;
      for (int q = 0; q < lim; ++q) {
        int j = __builtin_ctzll(rem);
        rem &= rem - 1;
        pairs[basep + q] = hi | (unsigned int)(scene * PPED + j);
      }
    }
  } else {
    unsigned short* Tsh = (unsigned short*)smem;
    bool isW2 = (b < 304);
    const float* src = isW2 ? Wm2 : Wp;
    unsigned short* dst = (unsigned short*)((char*)ws + (isW2 ? W2T_OFF : WPT_OFF));
    int c0 = (isW2 ? (b - 288) : (b - 304)) * 16;
#pragma unroll 4
    for (int it = 0; it < 32; ++it) {
      int k = it * 16 + (tid >> 4);
      int c = tid & 15;
      float v = src[(size_t)k * DD + c0 + c];
      Tsh[c * MHID + k] = isW2 ? f2h(v) : f2bf(v);
    }
    __syncthreads();
    unsigned int* dst32 = (unsigned int*)dst;
#pragma unroll 4
    for (int it = 0; it < 16; ++it) {
      int flat = it * 256 + tid;
      int c = flat >> 8;
      int ku = flat & 255;
      unsigned int lo = Tsh[c * MHID + 2 * ku];
      unsigned int hi = Tsh[c * MHID + 2 * ku + 1];
      int ks = ku >> 4;
      int g = (ku >> 2) & 3;
      int r = ku & 3;
      dst32[(size_t)(c0 + c) * 256 + g * 64 + ks * 4 + r] = lo | (hi << 16);
    }
  }
}

// ====== kCD: block owns 16 peds — layer2 tiles (LDS H2) + run-scan pool + final GEMM ======
__global__ __launch_bounds__(256) void kCD(const float* __restrict__ ws,
                                           const float* __restrict__ bm2,
                                           const float* __restrict__ bp,
                                           float* __restrict__ out) {
  __shared__ __align__(16) float catt[16 * 512 + 32];  // 32 KB cat tile (mx|mn)
  __shared__ __align__(16) char ashraw[16 * MHID * 2]; // 16 KB: Ash fp16 / H2t f32
  __shared__ int si[TILE], sjj[TILE];
  __shared__ int lse[17];
  int m0 = blockIdx.x * 16;
  int s = m0 >> 6;
  int tid = threadIdx.x;
  int w = tid >> 6, l = tid & 63;
  int lr = l & 15, lg = l >> 4;
  const unsigned short* u16 = (const unsigned short*)((const char*)ws + U16_OFF);
  const unsigned short* v16 = (const unsigned short*)((const char*)ws + V16_OFF);
  const _Float16* w2t = (const _Float16*)((const char*)ws + W2T_OFF);
  const short* wpt = (const short*)((const char*)ws + WPT_OFF);
  const unsigned int* pstart = (const unsigned int*)((const char*)ws + PSTART_OFF);
  const unsigned int* pcnt = (const unsigned int*)((const char*)ws + PCNT_OFF);
  const unsigned int* parr = (const unsigned int*)((const char*)ws + PAIR_OFF) + s * PPS;
  for (int i = tid; i < 16 * 512; i += 256) catt[i] = 0.f;
  if (tid < 16) {
    int n = m0 + tid;
    int ls = (int)pstart[n] - s * PPS;
    lse[tid] = ls;
    if (tid == 15) lse[16] = ls + (int)pcnt[n];
  }
  __syncthreads();
  int b0 = lse[0], b1 = lse[16];
  unsigned short* Ash = (unsigned short*)ashraw;
  float* H2t = (float*)ashraw;
  float rmx = 0.f, rmn = 0.f;
  int cur = -1;
  int col = tid;  // scan column
  float bias0 = bm2[w * 64 + lr];
  float bias1 = bm2[w * 64 + 16 + lr];
  float bias2 = bm2[w * 64 + 32 + lr];
  float bias3 = bm2[w * 64 + 48 + lr];
  for (int t0 = b0; t0 < b1; t0 += TILE) {
    __syncthreads();  // previous scan done (H2t/si free); catt init visible
    if (tid < TILE) {
      int p = t0 + tid;
      unsigned int pk = (p < b1) ? parr[p] : parr[b0];
      si[tid] = (int)(pk >> 16);
      sjj[tid] = (int)(pk & 0xFFFFu);
    }
    __syncthreads();
    // stage A: h1 = relu(U16[j] - V16[i]) fp16, XOR-swizzled
    {
      int pr = tid & 15, seg = tid >> 4;
      int jj = sjj[pr], ii = si[pr];
      const unsigned short* Up = u16 + (size_t)jj * MHID + seg * 32;
      const unsigned short* Vp = v16 + (size_t)ii * MHID + seg * 32;
      int swz = (pr & 7) << 3;
#pragma unroll
      for (int q = 0; q < 4; ++q) {
        half8 hu = *(const half8*)(Up + q * 8);
        half8 hv = *(const half8*)(Vp + q * 8);
        half8 d;
#pragma unroll
        for (int e = 0; e < 8; ++e) {
          _Float16 x = hu[e] - hv[e];
          d[e] = (x > (_Float16)0) ? x : (_Float16)0;
        }
        *(half8*)(Ash + ((pr * MHID + seg * 32 + q * 8) ^ swz)) = d;
      }
    }
    __syncthreads();
    // MFMA: wave w covers cols w*64 + cg*16 + lr, cg = 0..3
    int aswz = (lr & 7) << 3;
    f32x4 a0v = {0.f, 0.f, 0.f, 0.f}, a1v = {0.f, 0.f, 0.f, 0.f};
    f32x4 a2v = {0.f, 0.f, 0.f, 0.f}, a3v = {0.f, 0.f, 0.f, 0.f};
    const _Float16* wb0 = w2t + (size_t)(w * 64 + lr) * MHID + lg * 128;
#pragma unroll
    for (int ks = 0; ks < 16; ++ks) {
      half8 a = *(const half8*)(Ash + ((lr * MHID + ks * 32 + lg * 8) ^ aswz));
      half8 bf0 = *(const half8*)(wb0 + ks * 8);
      half8 bf1 = *(const half8*)(wb0 + 16 * MHID + ks * 8);
      half8 bf2 = *(const half8*)(wb0 + 32 * MHID + ks * 8);
      half8 bf3 = *(const half8*)(wb0 + 48 * MHID + ks * 8);
      a0v = __builtin_amdgcn_mfma_f32_16x16x32_f16(a, bf0, a0v, 0, 0, 0);
      a1v = __builtin_amdgcn_mfma_f32_16x16x32_f16(a, bf1, a1v, 0, 0, 0);
      a2v = __builtin_amdgcn_mfma_f32_16x16x32_f16(a, bf2, a2v, 0, 0, 0);
      a3v = __builtin_amdgcn_mfma_f32_16x16x32_f16(a, bf3, a3v, 0, 0, 0);
    }
    __syncthreads();  // all Ash reads complete; alias as H2t
#pragma unroll
    for (int r = 0; r < 4; ++r) {
      int row = lg * 4 + r;
      H2t[row * 256 + w * 64 + lr] = fmaxf(a0v[r] + bias0, 0.f);
      H2t[row * 256 + w * 64 + 16 + lr] = fmaxf(a1v[r] + bias1, 0.f);
      H2t[row * 256 + w * 64 + 32 + lr] = fmaxf(a2v[r] + bias2, 0.f);
      H2t[row * 256 + w * 64 + 48 + lr] = fmaxf(a3v[r] + bias3, 0.f);
    }
    __syncthreads();
    // run-scan pooling, state carried across tiles; thread owns col=tid
    int lastv = b1 - t0;
    if (lastv > TILE) lastv = TILE;
    for (int r = 0; r < lastv; ++r) {
      int ii = si[r];
      float v = H2t[r * 256 + col];
      if (ii != cur) {
        if (cur >= 0) {
          int li = cur - m0;
          int sz = (li & 7) << 2;
          catt[(li * 512 + col) ^ sz] = rmx;
          catt[(li * 512 + 256 + col) ^ sz] = rmn;
        }
        cur = ii;
        rmx = v;
        rmn = v;
      } else {
        rmx = fmaxf(rmx, v);
        rmn = fminf(rmn, v);
      }
    }
  }
  if (cur >= 0) {
    int li = cur - m0;
    int sz = (li & 7) << 2;
    catt[(li * 512 + col) ^ sz] = rmx;
    catt[(li * 512 + 256 + col) ^ sz] = rmn;
  }
  __syncthreads();
  // final GEMM: out[m0..m0+15] = relu(cat @ Wp + bp)
  int arow = l & 15, agrp = l >> 4;
  int aswz2 = (arow & 7) << 2;
  const short* wpb0 = wpt + (size_t)(w * 64 + arow) * MHID + agrp * 128;
  f32x4 acc0 = {0.f, 0.f, 0.f, 0.f}, acc1 = {0.f, 0.f, 0.f, 0.f};
  f32x4 acc2 = {0.f, 0.f, 0.f, 0.f}, acc3 = {0.f, 0.f, 0.f, 0.f};
#pragma unroll 4
  for (int ks = 0; ks < 16; ++ks) {
    int base = arow * 512 + ks * 32 + agrp * 8;
    float4 fa = *(const float4*)(catt + (base ^ aswz2));
    float4 fb = *(const float4*)(catt + ((base + 4) ^ aswz2));
    union {
      unsigned int u[4];
      short8 s;
    } av;
    av.u[0] = (unsigned int)f2bf(fa.x) | ((unsigned int)f2bf(fa.y) << 16);
    av.u[1] = (unsigned int)f2bf(fa.z) | ((unsigned int)f2bf(fa.w) << 16);
    av.u[2] = (unsigned int)f2bf(fb.x) | ((unsigned int)f2bf(fb.y) << 16);
    av.u[3] = (unsigned int)f2bf(fb.z) | ((unsigned int)f2bf(fb.w) << 16);
    short8 b0 = *(const short8*)(wpb0 + ks * 8);
    short8 b1 = *(const short8*)(wpb0 + 16 * MHID + ks * 8);
    short8 b2 = *(const short8*)(wpb0 + 32 * MHID + ks * 8);
    short8 b3 = *(const short8*)(wpb0 + 48 * MHID + ks * 8);
    acc0 = __builtin_amdgcn_mfma_f32_16x16x32_bf16(av.s, b0, acc0, 0, 0, 0);
    acc1 = __builtin_amdgcn_mfma_f32_16x16x32_bf16(av.s, b1, acc1, 0, 0, 0);
    acc2 = __builtin_amdgcn_mfma_f32_16x16x32_bf16(av.s, b2, acc2, 0, 0, 0);
    acc3 = __builtin_amdgcn_mfma_f32_16x16x32_bf16(av.s, b3, acc3, 0, 0, 0);
  }
#pragma unroll
  for (int t = 0; t < 4; ++t) {
    int colq = (w * 4 + t) * 16 + arow;
    float bias = bp[colq];
    f32x4 av = (t == 0) ? acc0 : (t == 1) ? acc1 : (t == 2) ? acc2 : acc3;
#pragma unroll
    for (int r = 0; r < 4; ++r) {
      int row = m0 + (l >> 4) * 4 + r;
      out[(size_t)row * DD + colq] = fmaxf(av[r] + bias, 0.f);
    }
  }
}

extern "C" void kernel_launch(void* const* d_in, const int* in_sizes, int n_in,
                              void* d_out, int out_size, void* d_ws, size_t ws_size,
                              hipStream_t stream) {
  const float* hstates = (const float*)d_in[0];
  const float* pos = (const float*)d_in[2];
  const float* vel = (const float*)d_in[3];
  const float* bpos = (const float*)d_in[4];
  const float* Ws = (const float*)d_in[5];
  const float* bs = (const float*)d_in[6];
  const float* Wv = (const float*)d_in[7];
  const float* bv = (const float*)d_in[8];
  const float* Wm1 = (const float*)d_in[9];
  const float* bm1 = (const float*)d_in[10];
  const float* Wm2 = (const float*)d_in[11];
  const float* bm2 = (const float*)d_in[12];
  const float* Wp = (const float*)d_in[13];
  const float* bp = (const float*)d_in[14];
  float* ws = (float*)d_ws;
  float* out = (float*)d_out;

  hipLaunchKernelGGL(kA, dim3(320), dim3(256), 0, stream, hstates, pos, vel, bpos, Ws, bs,
                     Wv, bv, Wm1, bm1, Wm2, Wp, ws);
  hipLaunchKernelGGL(kCD, dim3(NTOT / 16), dim3(256), 0, stream, ws, bm2, bp, out);
}